// Round 1
// 1133.904 us; speedup vs baseline: 1.0324x; 1.0324x over previous
//
#include <hip/hip_runtime.h>
#include <stdint.h>

// TinyGRU R10: wave-specialized layers. R9 post-mortem (active-CU scaled):
// MfmaUtil ~54%, VALU ~30%, stall ~16% -> ~950 cyc/step of unhidden latency
// on top of the invariant 1630-cyc weight stream (336 MFMA/block-step).
// All 8 waves ran identical streams -> phases aligned -> gate/write/barrier
// tail never overlapped MFMA issue. Now: waves 0-3 = layer0 only (36 MFMA,
// 2 row-tiles), waves 4-7 = layer1 only (48 MFMA). Round-robin wave->SIMD
// puts one of each per SIMD: L0's gate phase overlaps L1's MFMA issue.
// Per-SIMD issue conserved (84), LDS reads drop 80->56/step, barrier count
// matched across divergent paths (1025 each + initial sync).
// HC=144 / XC=72 so every ds_read_b128 is 16B-aligned (R4/R9 layout kept).

typedef _Float16 half_t;
typedef _Float16 half8 __attribute__((ext_vector_type(8)));
typedef __fp16  fp16x2 __attribute__((ext_vector_type(2)));
typedef float f32x4 __attribute__((ext_vector_type(4)));

#define SS 1024
#define CPB 4
#define NBLK 128
#define CT 4              // x chunk depth (steps)
#define HC 144            // h row stride (f16): 288B, 16B-aligned
#define XC 72             // x row stride (f16): 144B, 16B-aligned

#define MFMA16(a, b, c) __builtin_amdgcn_mfma_f32_16x16x32_f16(a, b, c, 0, 0, 0)

// lgkmcnt(0), vmcnt=63 (no wait), expcnt=7 (no wait)  [gfx9 encoding]
#define BAR() do { __builtin_amdgcn_sched_barrier(0);                 \
                   __builtin_amdgcn_s_waitcnt(0xC07F);                \
                   __builtin_amdgcn_s_barrier();                      \
                   __builtin_amdgcn_sched_barrier(0); } while (0)

__device__ __forceinline__ float sigmoidf_(float x) {
    return __builtin_amdgcn_rcpf(1.0f + __expf(-x));
}
__device__ __forceinline__ float tanhf_(float x) {
    return 1.0f - 2.0f * __builtin_amdgcn_rcpf(1.0f + __expf(2.0f * x));
}
union H8 { half8 v; fp16x2 p[4]; };
__device__ __forceinline__ half8 pack8(f32x4 a, f32x4 b) {
    H8 u;
    u.p[0] = __builtin_amdgcn_cvt_pkrtz(a[0], a[1]);
    u.p[1] = __builtin_amdgcn_cvt_pkrtz(a[2], a[3]);
    u.p[2] = __builtin_amdgcn_cvt_pkrtz(b[0], b[1]);
    u.p[3] = __builtin_amdgcn_cvt_pkrtz(b[2], b[3]);
    return u.v;
}
__device__ __forceinline__ half8 cvt8(const float* p) {
    return pack8(*(const f32x4*)p, *(const f32x4*)(p + 4));
}

__global__ __launch_bounds__(512, 2)
void gru_fused(const float* __restrict__ x,
               const float* __restrict__ Wih0, const float* __restrict__ Whh0,
               const float* __restrict__ bih0, const float* __restrict__ bhh0,
               const float* __restrict__ Wih1, const float* __restrict__ Whh1,
               const float* __restrict__ bih1, const float* __restrict__ bhh1,
               const float* __restrict__ fcw, const float* __restrict__ fcb,
               float* __restrict__ out)
{
    const int tid  = threadIdx.x;
    const int w    = tid >> 6;
    const int lane = tid & 63;
    const int quad = lane >> 4;
    const int col  = lane & 15;
    const int cb   = blockIdx.x * CPB;

    __shared__ alignas(16) half_t s_x[2][CT][CPB * XC];
    __shared__ alignas(16) half_t s_h0[2][CPB * HC];
    __shared__ alignas(16) half_t s_h1[2][CPB * HC];

    // zero h state: s_h0[0] (h0[-1]), s_h1[0] & s_h1[1] (h1[-2], h1[-1])
    for (int i = tid; i < CPB * HC; i += 512) {
        s_h0[0][i] = (half_t)0.0f;
        s_h1[0][i] = (half_t)0.0f;
        s_h1[1][i] = (half_t)0.0f;
    }

    // ---- x staging (unchanged schedule): tid<256 == layer-0 waves ----
    const int c  = (tid >> 6) & 3;
    const int sc = tid & 63;
    const float* xrow = x + (size_t)(cb + c) * SS * 64 + sc;
    float gq[CT];
    if (tid < 256) {
#pragma unroll
        for (int i = 0; i < CT; ++i) gq[i] = xrow[i * 64];
#pragma unroll
        for (int i = 0; i < CT; ++i)            // publish chunk 0
            s_x[0][i][c * XC + sc] = (half_t)gq[i];
#pragma unroll
        for (int i = 0; i < CT; ++i)            // issue chunk 1
            gq[i] = xrow[(CT + i) * 64];
    }
    __syncthreads();

    const int aoff  = (col >> 2) * HC + quad * 8;
    const int axoff = (col >> 2) * XC + quad * 8;

    if (w < 4) {
        // =========== layer-0 waves: 2 row-tiles, 36 MFMA/step ===========
        half8 Bx[2][3][2], Bh[2][3][4];
        float bR[2], bZ[2], bNI[2], bNH[2];
#pragma unroll
        for (int T = 0; T < 2; ++T) {
            const int rr = w * 16 + col + T * 64;
#pragma unroll
            for (int g = 0; g < 3; ++g) {
#pragma unroll
                for (int s = 0; s < 2; ++s)
                    Bx[T][g][s] = cvt8(Wih0 + (rr + g * 128) * 64 + s * 32 + quad * 8);
#pragma unroll
                for (int s = 0; s < 4; ++s)
                    Bh[T][g][s] = cvt8(Whh0 + (rr + g * 128) * 128 + s * 32 + quad * 8);
            }
            bR[T]  = bih0[rr] + bhh0[rr];
            bZ[T]  = bih0[128 + rr] + bhh0[128 + rr];
            bNI[T] = bih0[256 + rr];
            bNH[T] = bhh0[256 + rr];
        }
        float hp[2] = {0.0f, 0.0f};
        const int wr = w * 16 + col;

        for (int u = 0; u < SS; ++u) {
            const int cur = u & 1, nxt = cur ^ 1;
            f32x4 ar[2], az[2], ani[2], anh[2];
#pragma unroll
            for (int T = 0; T < 2; ++T) {
                ar[T]  = (f32x4){bR[T],  bR[T],  bR[T],  bR[T]};
                az[T]  = (f32x4){bZ[T],  bZ[T],  bZ[T],  bZ[T]};
                ani[T] = (f32x4){bNI[T], bNI[T], bNI[T], bNI[T]};
                anh[T] = (f32x4){bNH[T], bNH[T], bNH[T], bNH[T]};
            }
            const half_t* xb = &s_x[(u >> 2) & 1][u & 3][axoff];
            half8 ax0 = *(const half8*)(xb);
            half8 ax1 = *(const half8*)(xb + 32);
#pragma unroll
            for (int T = 0; T < 2; ++T) {
                ar[T]  = MFMA16(ax0, Bx[T][0][0], ar[T]);
                ar[T]  = MFMA16(ax1, Bx[T][0][1], ar[T]);
                az[T]  = MFMA16(ax0, Bx[T][1][0], az[T]);
                az[T]  = MFMA16(ax1, Bx[T][1][1], az[T]);
                ani[T] = MFMA16(ax0, Bx[T][2][0], ani[T]);
                ani[T] = MFMA16(ax1, Bx[T][2][1], ani[T]);
            }
#pragma unroll
            for (int s = 0; s < 4; ++s) {
                half8 ah = *(const half8*)&s_h0[cur][aoff + s * 32];
#pragma unroll
                for (int T = 0; T < 2; ++T) {
                    ar[T]  = MFMA16(ah, Bh[T][0][s], ar[T]);
                    az[T]  = MFMA16(ah, Bh[T][1][s], az[T]);
                    anh[T] = MFMA16(ah, Bh[T][2][s], anh[T]);
                }
            }
#pragma unroll
            for (int T = 0; T < 2; ++T) {
                float r = sigmoidf_(ar[T][0]);
                float z = sigmoidf_(az[T][0]);
                float n = tanhf_(ani[T][0] + r * anh[T][0]);
                hp[T] = n + z * (hp[T] - n);
                s_h0[nxt][quad * HC + wr + T * 64] = (half_t)hp[T];
            }
            if ((u & 3) == 3 && u + 1 < SS) {
                const int c1 = (u + 1) >> 2;
#pragma unroll
                for (int i = 0; i < CT; ++i)
                    s_x[c1 & 1][i][c * XC + sc] = (half_t)gq[i];
                const int base = (c1 + 1) * CT;
                if (base < SS) {
#pragma unroll
                    for (int i = 0; i < CT; ++i)
                        gq[i] = xrow[(size_t)(base + i) * 64];
                }
            }
            BAR();
        }
        BAR();           // pairs with layer-1's u==SS interval
    } else {
        // =========== layer-1 waves: 2 row-tiles, 48 MFMA/step ===========
        half8 Bx[2][3][4], Bh[2][3][4];
        float bR[2], bZ[2], bNI[2], bNH[2];
        const int w1 = w - 4;
#pragma unroll
        for (int T = 0; T < 2; ++T) {
            const int rr = w1 * 16 + col + T * 64;
#pragma unroll
            for (int g = 0; g < 3; ++g) {
#pragma unroll
                for (int s = 0; s < 4; ++s) {
                    Bx[T][g][s] = cvt8(Wih1 + (rr + g * 128) * 128 + s * 32 + quad * 8);
                    Bh[T][g][s] = cvt8(Whh1 + (rr + g * 128) * 128 + s * 32 + quad * 8);
                }
            }
            bR[T]  = bih1[rr] + bhh1[rr];
            bZ[T]  = bih1[128 + rr] + bhh1[128 + rr];
            bNI[T] = bih1[256 + rr];
            bNH[T] = bhh1[256 + rr];
        }
        float hp[2] = {0.0f, 0.0f};
        const int wr = w1 * 16 + col;

        BAR();           // pairs with layer-0's u==0 interval
        for (int u = 1; u <= SS; ++u) {
            const int cur = u & 1, nxt = cur ^ 1;
            f32x4 ar[2], az[2], ani[2], anh[2];
#pragma unroll
            for (int T = 0; T < 2; ++T) {
                ar[T]  = (f32x4){bR[T],  bR[T],  bR[T],  bR[T]};
                az[T]  = (f32x4){bZ[T],  bZ[T],  bZ[T],  bZ[T]};
                ani[T] = (f32x4){bNI[T], bNI[T], bNI[T], bNI[T]};
                anh[T] = (f32x4){bNH[T], bNH[T], bNH[T], bNH[T]};
            }
#pragma unroll
            for (int s = 0; s < 4; ++s) {
                half8 ah0 = *(const half8*)&s_h0[cur][aoff + s * 32];
                half8 ah1 = *(const half8*)&s_h1[cur][aoff + s * 32];
#pragma unroll
                for (int T = 0; T < 2; ++T) {
                    ar[T]  = MFMA16(ah0, Bx[T][0][s], ar[T]);
                    az[T]  = MFMA16(ah0, Bx[T][1][s], az[T]);
                    ani[T] = MFMA16(ah0, Bx[T][2][s], ani[T]);
                    ar[T]  = MFMA16(ah1, Bh[T][0][s], ar[T]);
                    az[T]  = MFMA16(ah1, Bh[T][1][s], az[T]);
                    anh[T] = MFMA16(ah1, Bh[T][2][s], anh[T]);
                }
            }
#pragma unroll
            for (int T = 0; T < 2; ++T) {
                float r = sigmoidf_(ar[T][0]);
                float z = sigmoidf_(az[T][0]);
                float n = tanhf_(ani[T][0] + r * anh[T][0]);
                hp[T] = n + z * (hp[T] - n);
                s_h1[nxt][quad * HC + wr + T * 64] = (half_t)hp[T];
            }
            BAR();
        }
    }

    // ---- FC epilogue: h1_final in s_h1[1] (u=1024: nxt=1) ----
    if (tid < 40) {
        const int ch = tid / 10, cl = tid - ch * 10;
        float acc = fcb[cl];
        const float* wrp = fcw + cl * 128;
        const half_t* hv = &s_h1[1][ch * HC];
#pragma unroll 8
        for (int k = 0; k < 128; ++k) acc += (float)hv[k] * wrp[k];
        out[(cb + ch) * 10 + cl] = acc;
    }
}

extern "C" void kernel_launch(void* const* d_in, const int* in_sizes, int n_in,
                              void* d_out, int out_size, void* d_ws, size_t ws_size,
                              hipStream_t stream) {
    const float* x    = (const float*)d_in[0];
    const float* Wih0 = (const float*)d_in[1];
    const float* Whh0 = (const float*)d_in[2];
    const float* bih0 = (const float*)d_in[3];
    const float* bhh0 = (const float*)d_in[4];
    const float* Wih1 = (const float*)d_in[5];
    const float* Whh1 = (const float*)d_in[6];
    const float* bih1 = (const float*)d_in[7];
    const float* bhh1 = (const float*)d_in[8];
    const float* fcw  = (const float*)d_in[9];
    const float* fcb  = (const float*)d_in[10];

    gru_fused<<<NBLK, 512, 0, stream>>>(x, Wih0, Whh0, bih0, bhh0,
                                        Wih1, Whh1, bih1, bhh1,
                                        fcw, fcb, (float*)d_out);
}

// Round 2
// 1004.376 us; speedup vs baseline: 1.1655x; 1.1290x over previous
//
#include <hip/hip_runtime.h>
#include <stdint.h>

// TinyGRU R11: batched x-side GEMMs at full MFMA N-utilization.
// R10 post-mortem: per-SIMD issue (84 MFMA/step ~1630cyc) binds, not phase
// alignment. Key insight: with CPB=4 the 16x16 MFMA N-dim holds only 4
// chains (4x replicated A rows) -> 75% of every MFMA discarded. The h*Whh
// recurrent parts can't avoid this (N=chains only), but the x-side GEMMs
// (xg0 = Wih0*x[t], xg1 = Wih1*h0[t]) are step-parallel: batch 4 timesteps
// packing N = 4 chains x 4 steps (A row i = (chain i>>2, step i&3), lane's
// acc[reg] = (chain quad, step reg) -- matches gate/store mapping exactly).
// Per-SIMD issue 84 -> 57 avg: j0: L0h24+L1h24+L1batch24=72, j1/j2: 48,
// j3: 48+L0batch12=60. L1 lags 4 steps (h0 ring of 8); L0-batch(g+1) at j3
// post-gate (drains into barrier shadow); L1-batch(G=g-1) at j0 pre-gate.
// x staged 2 groups ahead (2 chunks in prologue). All accs f32 (same math,
// regrouped). Barriers: 1028 both paths. Watch VGPR: L1 ~250/256 incl AGPR.

typedef _Float16 half_t;
typedef _Float16 half8 __attribute__((ext_vector_type(8)));
typedef __fp16  fp16x2 __attribute__((ext_vector_type(2)));
typedef float f32x4 __attribute__((ext_vector_type(4)));

#define SS 1024
#define CPB 4
#define NBLK 128
#define CT 4              // x chunk depth (steps per group)
#define HC 144            // h row stride (f16): 288B, 16B-aligned
#define XC 72             // x row stride (f16): 144B, 16B-aligned

#define MFMA16(a, b, c) __builtin_amdgcn_mfma_f32_16x16x32_f16(a, b, c, 0, 0, 0)

// lgkmcnt(0), vmcnt=63 (no wait), expcnt=7 (no wait)  [gfx9 encoding]
#define BAR() do { __builtin_amdgcn_sched_barrier(0);                 \
                   __builtin_amdgcn_s_waitcnt(0xC07F);                \
                   __builtin_amdgcn_s_barrier();                      \
                   __builtin_amdgcn_sched_barrier(0); } while (0)

__device__ __forceinline__ float sigmoidf_(float x) {
    return __builtin_amdgcn_rcpf(1.0f + __expf(-x));
}
__device__ __forceinline__ float tanhf_(float x) {
    return 1.0f - 2.0f * __builtin_amdgcn_rcpf(1.0f + __expf(2.0f * x));
}
union H8 { half8 v; fp16x2 p[4]; };
__device__ __forceinline__ half8 pack8(f32x4 a, f32x4 b) {
    H8 u;
    u.p[0] = __builtin_amdgcn_cvt_pkrtz(a[0], a[1]);
    u.p[1] = __builtin_amdgcn_cvt_pkrtz(a[2], a[3]);
    u.p[2] = __builtin_amdgcn_cvt_pkrtz(b[0], b[1]);
    u.p[3] = __builtin_amdgcn_cvt_pkrtz(b[2], b[3]);
    return u.v;
}
__device__ __forceinline__ half8 cvt8(const float* p) {
    return pack8(*(const f32x4*)p, *(const f32x4*)(p + 4));
}

__global__ __launch_bounds__(512, 2)
void gru_fused(const float* __restrict__ x,
               const float* __restrict__ Wih0, const float* __restrict__ Whh0,
               const float* __restrict__ bih0, const float* __restrict__ bhh0,
               const float* __restrict__ Wih1, const float* __restrict__ Whh1,
               const float* __restrict__ bih1, const float* __restrict__ bhh1,
               const float* __restrict__ fcw, const float* __restrict__ fcb,
               float* __restrict__ out)
{
    const int tid  = threadIdx.x;
    const int w    = tid >> 6;
    const int lane = tid & 63;
    const int quad = lane >> 4;
    const int col  = lane & 15;
    const int c3   = col & 3;      // batch: step-in-group
    const int ch4  = col >> 2;     // batch & step: chain
    const int cb   = blockIdx.x * CPB;

    __shared__ alignas(16) half_t s_x[2][CT][CPB * XC];
    __shared__ alignas(16) half_t s_h0[8][CPB * HC];   // 8-deep ring
    __shared__ alignas(16) half_t s_h1[2][CPB * HC];

    // zero: h0[-1] lives in ring slot 7; h1[-1] in parity slot 1
    for (int i = tid; i < CPB * HC; i += 512) {
        s_h0[7][i] = (half_t)0.0f;
        s_h1[1][i] = (half_t)0.0f;
    }

    // ---- x staging: 2 chunks ahead. Publish chunks 0,1; chunk 2 -> gq ----
    const int c  = (tid >> 6) & 3;
    const int sc = tid & 63;
    const float* xrow = x + (size_t)(cb + c) * SS * 64 + sc;
    float gq[CT];
    if (tid < 256) {
        float t[CT];
#pragma unroll
        for (int i = 0; i < CT; ++i) t[i] = xrow[i * 64];
#pragma unroll
        for (int i = 0; i < CT; ++i) s_x[0][i][c * XC + sc] = (half_t)t[i];
#pragma unroll
        for (int i = 0; i < CT; ++i) t[i] = xrow[(CT + i) * 64];
#pragma unroll
        for (int i = 0; i < CT; ++i) s_x[1][i][c * XC + sc] = (half_t)t[i];
#pragma unroll
        for (int i = 0; i < CT; ++i) gq[i] = xrow[(2 * CT + i) * 64];
    }
    __syncthreads();

    const int aoff = ch4 * HC + quad * 8;   // per-step h-read base (halves)

    if (w < 4) {
        // ================= layer-0 waves =================
        half8 Bx[2][3][2], Bh[2][3][4];
        float bR[2], bZ[2], bNI[2], bNH[2];
#pragma unroll
        for (int T = 0; T < 2; ++T) {
            const int rr = w * 16 + col + T * 64;
#pragma unroll
            for (int gg = 0; gg < 3; ++gg) {
#pragma unroll
                for (int s = 0; s < 2; ++s)
                    Bx[T][gg][s] = cvt8(Wih0 + (rr + gg * 128) * 64 + s * 32 + quad * 8);
#pragma unroll
                for (int s = 0; s < 4; ++s)
                    Bh[T][gg][s] = cvt8(Whh0 + (rr + gg * 128) * 128 + s * 32 + quad * 8);
            }
            bR[T]  = bih0[rr] + bhh0[rr];
            bZ[T]  = bih0[128 + rr] + bhh0[128 + rr];
            bNI[T] = bih0[256 + rr];
            bNH[T] = bhh0[256 + rr];
        }
        float hp[2] = {0.0f, 0.0f};
        const int wr_ = w * 16 + col;
        f32x4 XAr[2], XAz[2], XAn[2];   // batched xg0 for current group (+bias)

#define L0_BATCH(BUF)                                                        \
        {                                                                    \
            const half_t* xp = &s_x[(BUF)][c3][ch4 * XC + quad * 8];         \
            half8 a0 = *(const half8*)xp;                                    \
            half8 a1 = *(const half8*)(xp + 32);                             \
            _Pragma("unroll")                                                \
            for (int T = 0; T < 2; ++T) {                                    \
                XAr[T] = (f32x4){bR[T],  bR[T],  bR[T],  bR[T]};             \
                XAz[T] = (f32x4){bZ[T],  bZ[T],  bZ[T],  bZ[T]};             \
                XAn[T] = (f32x4){bNI[T], bNI[T], bNI[T], bNI[T]};            \
                XAr[T] = MFMA16(a0, Bx[T][0][0], XAr[T]);                    \
                XAr[T] = MFMA16(a1, Bx[T][0][1], XAr[T]);                    \
                XAz[T] = MFMA16(a0, Bx[T][1][0], XAz[T]);                    \
                XAz[T] = MFMA16(a1, Bx[T][1][1], XAz[T]);                    \
                XAn[T] = MFMA16(a0, Bx[T][2][0], XAn[T]);                    \
                XAn[T] = MFMA16(a1, Bx[T][2][1], XAn[T]);                    \
            }                                                                \
        }

        L0_BATCH(0);   // xg0 for group 0 (reads chunk 0, pre-synced)

        for (int g = 0; g < 256; ++g) {
#pragma unroll
            for (int j = 0; j < 4; ++j) {
                const int u = 4 * g + j;
                f32x4 ar[2], az[2], anh[2];
#pragma unroll
                for (int T = 0; T < 2; ++T) {
                    ar[T]  = (f32x4){0.f, 0.f, 0.f, 0.f};
                    az[T]  = (f32x4){0.f, 0.f, 0.f, 0.f};
                    anh[T] = (f32x4){bNH[T], bNH[T], bNH[T], bNH[T]};
                }
                const half_t* hb = &s_h0[(u - 1) & 7][aoff];
#pragma unroll
                for (int s = 0; s < 4; ++s) {
                    half8 ah = *(const half8*)(hb + s * 32);
#pragma unroll
                    for (int T = 0; T < 2; ++T) {
                        ar[T]  = MFMA16(ah, Bh[T][0][s], ar[T]);
                        az[T]  = MFMA16(ah, Bh[T][1][s], az[T]);
                        anh[T] = MFMA16(ah, Bh[T][2][s], anh[T]);
                    }
                }
#pragma unroll
                for (int T = 0; T < 2; ++T) {
                    float r = sigmoidf_(ar[T][0] + XAr[T][j]);
                    float z = sigmoidf_(az[T][0] + XAz[T][j]);
                    float n = tanhf_(XAn[T][j] + r * anh[T][0]);
                    hp[T] = n + z * (hp[T] - n);
                    s_h0[u & 7][quad * HC + wr_ + T * 64] = (half_t)hp[T];
                }
                if (j == 3) {
                    if (g + 2 < 256) {        // publish chunk g+2 -> buf g&1
#pragma unroll
                        for (int i = 0; i < CT; ++i)
                            s_x[g & 1][i][c * XC + sc] = (half_t)gq[i];
                    }
                    if (g + 3 < 256) {        // issue load chunk g+3
#pragma unroll
                        for (int i = 0; i < CT; ++i)
                            gq[i] = xrow[(size_t)((g + 3) * CT + i) * 64];
                    }
                    if (g < 255) L0_BATCH((g + 1) & 1);   // xg0 for group g+1
                }
                BAR();
            }
        }
        BAR(); BAR(); BAR(); BAR();   // intervals 1024..1027 (L1 tail)
#undef L0_BATCH
    } else {
        // ================= layer-1 waves (lag 4) =================
        const int w1 = w - 4;
        half8 Bx[2][3][4], Bh[2][3][4];
        float bR[2], bZ[2], bNI[2], bNH[2];
#pragma unroll
        for (int T = 0; T < 2; ++T) {
            const int rr = w1 * 16 + col + T * 64;
#pragma unroll
            for (int gg = 0; gg < 3; ++gg) {
#pragma unroll
                for (int s = 0; s < 4; ++s) {
                    Bx[T][gg][s] = cvt8(Wih1 + (rr + gg * 128) * 128 + s * 32 + quad * 8);
                    Bh[T][gg][s] = cvt8(Whh1 + (rr + gg * 128) * 128 + s * 32 + quad * 8);
                }
            }
            bR[T]  = bih1[rr] + bhh1[rr];
            bZ[T]  = bih1[128 + rr] + bhh1[128 + rr];
            bNI[T] = bih1[256 + rr];
            bNH[T] = bhh1[256 + rr];
        }
        float hp[2] = {0.0f, 0.0f};
        const int wr_ = w1 * 16 + col;
        f32x4 Yr[2], Yz[2], Yn[2];   // batched xg1 for current L1-group (+bias)

        BAR(); BAR(); BAR(); BAR();  // intervals 0..3 (L0 warms up)
        for (int g = 1; g <= 256; ++g) {
#pragma unroll
            for (int j = 0; j < 4; ++j) {
                if (j == 0) {
                    // batch xg1 for L1-group g-1: reads h0[4(g-1)+c3],
                    // ring slots sb..sb+3 (disjoint from L0's write slot).
                    const int slot = ((g - 1) & 1) * 4 + c3;
                    const half_t* bp = &s_h0[slot][aoff];
#pragma unroll
                    for (int T = 0; T < 2; ++T) {
                        Yr[T] = (f32x4){bR[T],  bR[T],  bR[T],  bR[T]};
                        Yz[T] = (f32x4){bZ[T],  bZ[T],  bZ[T],  bZ[T]};
                        Yn[T] = (f32x4){bNI[T], bNI[T], bNI[T], bNI[T]};
                    }
#pragma unroll
                    for (int s = 0; s < 4; ++s) {
                        half8 ax = *(const half8*)(bp + s * 32);
#pragma unroll
                        for (int T = 0; T < 2; ++T) {
                            Yr[T] = MFMA16(ax, Bx[T][0][s], Yr[T]);
                            Yz[T] = MFMA16(ax, Bx[T][1][s], Yz[T]);
                            Yn[T] = MFMA16(ax, Bx[T][2][s], Yn[T]);
                        }
                    }
                }
                // recurrent h1 part for step v = 4(g-1)+j
                f32x4 ar[2], az[2], anh[2];
#pragma unroll
                for (int T = 0; T < 2; ++T) {
                    ar[T]  = (f32x4){0.f, 0.f, 0.f, 0.f};
                    az[T]  = (f32x4){0.f, 0.f, 0.f, 0.f};
                    anh[T] = (f32x4){bNH[T], bNH[T], bNH[T], bNH[T]};
                }
                const half_t* hb = &s_h1[(j + 1) & 1][aoff];
#pragma unroll
                for (int s = 0; s < 4; ++s) {
                    half8 ah = *(const half8*)(hb + s * 32);
#pragma unroll
                    for (int T = 0; T < 2; ++T) {
                        ar[T]  = MFMA16(ah, Bh[T][0][s], ar[T]);
                        az[T]  = MFMA16(ah, Bh[T][1][s], az[T]);
                        anh[T] = MFMA16(ah, Bh[T][2][s], anh[T]);
                    }
                }
#pragma unroll
                for (int T = 0; T < 2; ++T) {
                    float r = sigmoidf_(ar[T][0] + Yr[T][j]);
                    float z = sigmoidf_(az[T][0] + Yz[T][j]);
                    float n = tanhf_(Yn[T][j] + r * anh[T][0]);
                    hp[T] = n + z * (hp[T] - n);
                    s_h1[j & 1][quad * HC + wr_ + T * 64] = (half_t)hp[T];
                }
                BAR();
            }
        }
    }

    // ---- FC epilogue: h1[1023] in s_h1[1] (1023 & 1 == 1) ----
    if (tid < 40) {
        const int ch = tid / 10, cl = tid - ch * 10;
        float acc = fcb[cl];
        const float* wrp = fcw + cl * 128;
        const half_t* hv = &s_h1[1][ch * HC];
#pragma unroll 8
        for (int k = 0; k < 128; ++k) acc += (float)hv[k] * wrp[k];
        out[(cb + ch) * 10 + cl] = acc;
    }
}

extern "C" void kernel_launch(void* const* d_in, const int* in_sizes, int n_in,
                              void* d_out, int out_size, void* d_ws, size_t ws_size,
                              hipStream_t stream) {
    const float* x    = (const float*)d_in[0];
    const float* Wih0 = (const float*)d_in[1];
    const float* Whh0 = (const float*)d_in[2];
    const float* bih0 = (const float*)d_in[3];
    const float* bhh0 = (const float*)d_in[4];
    const float* Wih1 = (const float*)d_in[5];
    const float* Whh1 = (const float*)d_in[6];
    const float* bih1 = (const float*)d_in[7];
    const float* bhh1 = (const float*)d_in[8];
    const float* fcw  = (const float*)d_in[9];
    const float* fcb  = (const float*)d_in[10];

    gru_fused<<<NBLK, 512, 0, stream>>>(x, Wih0, Whh0, bih0, bhh0,
                                        Wih1, Whh1, bih1, bhh1,
                                        fcw, fcb, (float*)d_out);
}